// Round 13
// baseline (242.540 us; speedup 1.0000x reference)
//
#include <hip/hip_runtime.h>

// B=4, C=256, H=W=64 (N=4096). QKV 1x1conv -> spatial attention (softmax over
// j only => independent per-64-key-chunk softmax) -> channel LayerNorm.
// f16 MFMA 32x32x16, fp32 accumulation.
//
// R19: gemm restructured so x2 is staged ONCE. Grid 512 interleaved: even
// ids = Q blocks (x1, unchanged R18 logic), odd ids = KV blocks (stage x2
// tile once, K-pass mfma(x,w)->DsA and V-pass mfma(w,x)->DsB, both weight
// sets prefetched a round ahead, ONE barrier-pair per round). Halves KV
// staging instructions, removes 16.8MB duplicated x2 HBM reads. All staging/
// MFMA/epilogue/store code byte-for-byte from the proven R18 kernel.
// attn: R16 verbatim (105.9us x3). wconv/merge_ln unchanged (proven).

#define CDIM 256
#define NPOS 4096
#define BATCH 4
#define EPSV 1e-5f

typedef _Float16 f16;
typedef __attribute__((ext_vector_type(4))) _Float16 f16x4;
typedef __attribute__((ext_vector_type(8))) _Float16 f16x8;
typedef __attribute__((ext_vector_type(4))) float f32x4;
typedef __attribute__((ext_vector_type(16))) float f32x16;

#define WST       264   // f16; 528B = 33*16 -> b128-aligned rows
#define QK_STRIDE 264   // f16 K-tile rows
#define V_STRIDE  72    // f16 Vs/P rows; 144B = 9*16
#define DQ_STRIDE 72
#define F_STRIDE  68    // merge kernel LDS stride (f32)

// LDS-only barrier: prior LDS ops complete, global loads stay in flight.
#define LBAR() asm volatile("s_waitcnt lgkmcnt(0)\n\ts_barrier" ::: "memory")

// MFMA 32x32x16 f16:
//   A: lane l holds A[m=l&31][k=(l>>5)*8+j]
//   B: lane l holds B[k=(l>>5)*8+j][n=l&31]   (same register layout as A)
//   C/D: lane l, reg r -> row m=(r&3)+8*(r>>2)+4*(l>>5), col n=l&31
//
// Fragment-major W: Wf[(pr*8 + q*2 + ot)*8192 + (ks*64 + lane)*8], lane l
// covering W[o = q*64 + ot*32 + (l&31)][c = ks*16 + (l>>5)*8 + 0..7].

static __device__ __forceinline__ f16x8 cvt8(const float* __restrict__ p) {
    float4 w0 = *(const float4*)p;
    float4 w1 = *(const float4*)(p + 4);
    f16x8 r;
    r[0] = (f16)w0.x; r[1] = (f16)w0.y; r[2] = (f16)w0.z; r[3] = (f16)w0.w;
    r[4] = (f16)w1.x; r[5] = (f16)w1.y; r[6] = (f16)w1.z; r[7] = (f16)w1.w;
    return r;
}

// ---------------------------------------------------------------------------
// wconv: 24 blocks = pr*8 + q*2 + ot. fp32 weights -> fragment-major f16 Wf.
// ---------------------------------------------------------------------------
__global__ __launch_bounds__(256, 4) void wconv_kernel(
    const float* __restrict__ qw, const float* __restrict__ kw,
    const float* __restrict__ vw, f16* __restrict__ Wf)
{
    const int id = blockIdx.x;           // 0..23
    const int t  = threadIdx.x;
    const int pr = id >> 3;
    const int q  = (id >> 1) & 3;
    const int ot = id & 1;
    const float* W = (pr == 0 ? qw : pr == 1 ? kw : vw);
    f16* D = Wf + (size_t)id * 8192;
    #pragma unroll
    for (int i = 0; i < 4; ++i) {
        int idx = t + i * 256;           // 0..1023 = ks*64 + l
        int ks = idx >> 6, l = idx & 63;
        const float* src = W + (size_t)(q * 64 + ot * 32 + (l & 31)) * CDIM
                             + ks * 16 + (l >> 5) * 8;
        *(f16x8*)(D + (size_t)idx * 8) = cvt8(src);
    }
}

// ---------------------------------------------------------------------------
// gemm: grid 512, interleaved. Even id = Q block (x1), odd id = KV block
// (x2 staged once, K AND V computed). (256,2) -> 2 blocks/CU, one pass.
// W fragments direct from fragment-major global, prefetched a round ahead.
// ---------------------------------------------------------------------------
__global__ __launch_bounds__(256, 2) void gemm_kernel(
    const float* __restrict__ x1, const float* __restrict__ x2,
    const f16* __restrict__ Wf,
    const float* __restrict__ qb, const float* __restrict__ kb,
    const float* __restrict__ vb,
    f16* __restrict__ Qg, f16* __restrict__ Kg, f16* __restrict__ Vg)
{
    __shared__ f16 Xs[64 * WST];          // 33792 B
    __shared__ f16 DsA[64 * DQ_STRIDE];   //  9216 B
    __shared__ f16 DsB[64 * DQ_STRIDE];   //  9216 B
    __shared__ float biasA[256], biasB[256]; // 2048 B  (total 54272 B)

    const int id   = blockIdx.x;
    const int isKV = id & 1;
    const int rem  = id >> 1;
    const int b    = rem >> 6;
    const int p0   = (rem & 63) << 6;
    const float* xsrc = (isKV ? x2 : x1) + (size_t)b * CDIM * NPOS + p0;

    const int t = threadIdx.x, w = t >> 6, l = t & 63, lm = l & 31, lh = l >> 5;
    const int pt = w & 1, ot = w >> 1;

    if (isKV) { biasA[t] = kb[t]; biasB[t] = vb[t]; }
    else      { biasA[t] = qb[t]; }

    const f16* WfQ = Wf + (size_t)ot * 8192;             // pr=0
    const f16* WfK = Wf + 65536  + (size_t)ot * 8192;    // pr=1
    const f16* WfV = Wf + 131072 + (size_t)ot * 8192;    // pr=2

    // weight fragments, prefetched (Q path uses wk only)
    f16x8 wk[16], wv[16];
    if (isKV) {
        #pragma unroll
        for (int ks = 0; ks < 16; ++ks) {
            wk[ks] = *(const f16x8*)(WfK + (size_t)ks * 512 + l * 8);
            wv[ks] = *(const f16x8*)(WfV + (size_t)ks * 512 + l * 8);
        }
    } else {
        #pragma unroll
        for (int ks = 0; ks < 16; ++ks)
            wk[ks] = *(const f16x8*)(WfQ + (size_t)ks * 512 + l * 8);
    }

    // Xs[p][c] <- x[b][c][p0+p], fp32->f16 (transpose via staging, proven)
    #pragma unroll
    for (int g = 0; g < 8; ++g) {
        f16x8 h;
        #pragma unroll
        for (int j = 0; j < 8; ++j)
            h[j] = (f16)xsrc[(size_t)(w * 64 + g * 8 + j) * NPOS + l];
        *(f16x8*)&Xs[l * WST + w * 64 + g * 8] = h;
    }
    LBAR();   // Xs ready (weight loads stay in flight)

    for (int q = 0; q < 4; ++q) {
        if (!isKV) {
            // ---- Q block: R18 logic with DsA ----
            f32x16 accA = {}, accB = {};
            #pragma unroll
            for (int ks = 0; ks < 16; ks += 2) {
                f16x8 x0  = *(const f16x8*)&Xs[(pt * 32 + lm) * WST + ks * 16 + lh * 8];
                f16x8 x1v = *(const f16x8*)&Xs[(pt * 32 + lm) * WST + (ks + 1) * 16 + lh * 8];
                accA = __builtin_amdgcn_mfma_f32_32x32x16_f16(x0, wk[ks], accA, 0, 0, 0);
                accB = __builtin_amdgcn_mfma_f32_32x32x16_f16(x1v, wk[ks + 1], accB, 0, 0, 0);
            }
            if (q < 3) {
                #pragma unroll
                for (int ks = 0; ks < 16; ++ks)
                    wk[ks] = *(const f16x8*)(WfQ + (size_t)(q + 1) * 16384
                                                 + (size_t)ks * 512 + l * 8);
            }
            {
                int o_l = ot * 32 + lm;
                float bv = biasA[q * 64 + o_l];
                #pragma unroll
                for (int r = 0; r < 16; ++r) {
                    int p_l = pt * 32 + (r & 3) + 8 * (r >> 2) + 4 * lh;
                    DsA[p_l * DQ_STRIDE + o_l] = (f16)(accA[r] + accB[r] + bv);
                }
            }
            LBAR();
            #pragma unroll
            for (int j = 0; j < 2; ++j) {
                int row = (t >> 3) + j * 32;
                int cc  = (t & 7) * 8;
                f16x8 vd = *(const f16x8*)&DsA[row * DQ_STRIDE + cc];
                *(f16x8*)(Qg + ((size_t)(b * NPOS + p0 + row)) * CDIM + q * 64 + cc) = vd;
            }
            LBAR();
        } else {
            // ---- KV block: K-pass -> DsA, V-pass -> DsB, shared Xs ----
            f32x16 accA = {}, accB = {};
            #pragma unroll
            for (int ks = 0; ks < 16; ks += 2) {
                f16x8 x0  = *(const f16x8*)&Xs[(pt * 32 + lm) * WST + ks * 16 + lh * 8];
                f16x8 x1v = *(const f16x8*)&Xs[(pt * 32 + lm) * WST + (ks + 1) * 16 + lh * 8];
                accA = __builtin_amdgcn_mfma_f32_32x32x16_f16(x0, wk[ks], accA, 0, 0, 0);
                accB = __builtin_amdgcn_mfma_f32_32x32x16_f16(x1v, wk[ks + 1], accB, 0, 0, 0);
            }
            {
                int o_l = ot * 32 + lm;
                float bv = biasA[q * 64 + o_l];
                #pragma unroll
                for (int r = 0; r < 16; ++r) {
                    int p_l = pt * 32 + (r & 3) + 8 * (r >> 2) + 4 * lh;
                    DsA[p_l * DQ_STRIDE + o_l] = (f16)(accA[r] + accB[r] + bv);
                }
            }
            // V-pass (weights as A-operand -> rows = out-channel)
            f32x16 accC = {}, accD = {};
            #pragma unroll
            for (int ks = 0; ks < 16; ks += 2) {
                f16x8 x0  = *(const f16x8*)&Xs[(pt * 32 + lm) * WST + ks * 16 + lh * 8];
                f16x8 x1v = *(const f16x8*)&Xs[(pt * 32 + lm) * WST + (ks + 1) * 16 + lh * 8];
                accC = __builtin_amdgcn_mfma_f32_32x32x16_f16(wv[ks], x0, accC, 0, 0, 0);
                accD = __builtin_amdgcn_mfma_f32_32x32x16_f16(wv[ks + 1], x1v, accD, 0, 0, 0);
            }
            if (q < 3) {
                #pragma unroll
                for (int ks = 0; ks < 16; ++ks) {
                    wk[ks] = *(const f16x8*)(WfK + (size_t)(q + 1) * 16384
                                                 + (size_t)ks * 512 + l * 8);
                    wv[ks] = *(const f16x8*)(WfV + (size_t)(q + 1) * 16384
                                                 + (size_t)ks * 512 + l * 8);
                }
            }
            #pragma unroll
            for (int r = 0; r < 16; ++r) {
                int o_l = ot * 32 + (r & 3) + 8 * (r >> 2) + 4 * lh;
                DsB[o_l * DQ_STRIDE + pt * 32 + lm] =
                    (f16)(accC[r] + accD[r] + biasB[q * 64 + o_l]);
            }
            LBAR();
            #pragma unroll
            for (int j = 0; j < 2; ++j) {
                int row = (t >> 3) + j * 32;
                int cc  = (t & 7) * 8;
                f16x8 vk = *(const f16x8*)&DsA[row * DQ_STRIDE + cc];
                f16x8 vv = *(const f16x8*)&DsB[row * DQ_STRIDE + cc];
                *(f16x8*)(Kg + ((size_t)(b * NPOS + p0 + row)) * CDIM + q * 64 + cc) = vk;
                *(f16x8*)(Vg + ((size_t)(b * CDIM + q * 64 + row)) * NPOS + p0 + cc) = vv;
            }
            LBAR();
        }
    }
}

// ---------------------------------------------------------------------------
// attn: R16 verbatim (proven 105.9us x3). grid 512, 256 thr = 4 waves,
// (256,2), 2 blocks/CU co-resident, bijective XCD swizzle. Per chunk: K+V
// reg-prefetch -> LDS commit; swapped QK^T (S^T in registers); in-register
// softmax with LSE cross-wave merge; P f16 tile -> LDS; PV from Vs+P
// ds_read_b128. 3 LDS-only barriers. Partial F fp32 [bq][half][256c][64p].
// ---------------------------------------------------------------------------
__global__ __launch_bounds__(256, 2) void attn_kernel(
    const f16* __restrict__ Qg, const f16* __restrict__ Kg, const f16* __restrict__ Vg,
    float* __restrict__ Fp)
{
    __shared__ f16   Ks[64 * QK_STRIDE];   // 33792 B  [key][c]
    __shared__ f16   Vs[256 * V_STRIDE];   // 36864 B  [c][j]
    __shared__ f16   Pl[64 * V_STRIDE];    //  9216 B  [p][key]
    __shared__ float RedM[2][64], RedS[2][64];  // 1024 B

    const int t    = threadIdx.x;
    const int L    = (int)((blockIdx.x & 7) * 64 + (blockIdx.x >> 3)); // XCD swizzle
    const int grp  = L >> 6;         // 0..7 = (b<<1 | half)
    const int b    = grp >> 1;
    const int half = grp & 1;
    const int qt   = L & 63;
    const int p0   = qt << 6;
    const int bq   = b * 64 + qt;
    const int w    = t >> 6;         // 0..3
    const int l    = t & 63;
    const int lm   = l & 31;
    const int lh   = l >> 5;
    const int spt  = w & 1;          // wave's p-tile
    const int skt  = w >> 1;         // wave's key-tile

    // Q fragments (MFMA B-operand; layout identical to A-operand)
    f16x8 qf[16];
    {
        const f16* qptr = Qg + (size_t)(b * NPOS + p0 + spt * 32 + lm) * CDIM + lh * 8;
        #pragma unroll
        for (int ks = 0; ks < 16; ++ks) qf[ks] = *(const f16x8*)(qptr + ks * 16);
    }

    // K prefetch registers (rows coalesced from Kg[n][c])
    const int kr = t >> 5, koff = (t & 31) * 8;
    f16x8 kreg[8];
    auto issue_k = [&](int ch) {
        const int i0 = ch * 64;
        #pragma unroll
        for (int r = 0; r < 8; ++r)
            kreg[r] = *(const f16x8*)(Kg + (size_t)(b * NPOS + i0 + r * 8 + kr) * CDIM + koff);
    };

    // V prefetch registers (128B-contiguous runs per c-row from Vg[c][n])
    const int vr = t >> 3;           // c row within each 32-row group
    const int vc = (t & 7) * 8;      // halfword col within chunk
    f16x8 vreg[8];
    auto issue_v = [&](int ch) {
        const int i0 = ch * 64;
        #pragma unroll
        for (int i = 0; i < 8; ++i)
            vreg[i] = *(const f16x8*)(Vg + (size_t)(b * CDIM + i * 32 + vr) * NPOS + i0 + vc);
    };

    issue_k(half * 32);
    issue_v(half * 32);

    f32x16 facc[4] = {};      // per-wave F acc: [ci=c-subtile(2)][pj=p-tile(2)]

    for (int it = 0; it < 32; ++it) {
        const int ch = half * 32 + it;

        // commit prefetched K to LDS, then issue next chunk's K loads
        #pragma unroll
        for (int r = 0; r < 8; ++r)
            *(f16x8*)&Ks[(r * 8 + kr) * QK_STRIDE + koff] = kreg[r];
        if (it < 31) issue_k(ch + 1);
        LBAR();   // A: Ks ready; prev PV's Vs/Pl reads done

        // commit prefetched V to LDS, then issue next chunk's V loads
        #pragma unroll
        for (int i = 0; i < 8; ++i)
            *(f16x8*)&Vs[(i * 32 + vr) * V_STRIDE + vc] = vreg[i];
        if (it < 31) issue_v(ch + 1);

        // S^T = K Q^T : D[m=key][n=p]; lane holds S^T[16 keys][p=spt*32+lm]
        f32x16 st = {};
        __builtin_amdgcn_s_setprio(1);
        #pragma unroll
        for (int ks = 0; ks < 16; ++ks) {
            f16x8 kf = *(const f16x8*)&Ks[(skt * 32 + lm) * QK_STRIDE + ks * 16 + lh * 8];
            st = __builtin_amdgcn_mfma_f32_32x32x16_f16(kf, qf[ks], st, 0, 0, 0);
        }
        __builtin_amdgcn_s_setprio(0);

        // in-register softmax over this key-tile (32 keys: 16 own + lh-partner)
        float mx = st[0];
        #pragma unroll
        for (int r = 1; r < 16; ++r) mx = fmaxf(mx, st[r]);
        mx = fmaxf(mx, __shfl_xor(mx, 32));
        float ss = 0.f;
        #pragma unroll
        for (int r = 0; r < 16; ++r) {
            float e = __expf(st[r] - mx);
            st[r] = e;
            ss += e;
        }
        ss += __shfl_xor(ss, 32);
        if (lh == 0) { RedM[skt][spt * 32 + lm] = mx; RedS[skt][spt * 32 + lm] = ss; }
        LBAR();   // B: Red exchange ready

        // LSE merge with partner key-tile wave -> full 64-key softmax
        float mo = RedM[skt ^ 1][spt * 32 + lm];
        float so = RedS[skt ^ 1][spt * 32 + lm];
        float M  = fmaxf(mx, mo);
        float S  = ss * __expf(mx - M) + so * __expf(mo - M);
        float scale = __expf(mx - M) * __builtin_amdgcn_rcpf(S);

        // P[key][p] f16 -> Pl[p][key]; lane's 16 keys = 4 runs of 4 consecutive
        #pragma unroll
        for (int rq = 0; rq < 4; ++rq) {
            f16x4 pk;
            #pragma unroll
            for (int q2 = 0; q2 < 4; ++q2) pk[q2] = (f16)(st[rq * 4 + q2] * scale);
            *(f16x4*)&Pl[(spt * 32 + lm) * V_STRIDE + skt * 32 + rq * 8 + lh * 4] = pk;
        }
        LBAR();   // C: Pl ready; Vs commits drained

        // F += V P : D[m=c][n=p]; A=Vs rows, B=Pl rows (both b128-contiguous)
        __builtin_amdgcn_s_setprio(1);
        #pragma unroll
        for (int kb2 = 0; kb2 < 4; ++kb2) {
            f16x8 pf0 = *(const f16x8*)&Pl[lm * V_STRIDE + kb2 * 16 + lh * 8];
            f16x8 pf1 = *(const f16x8*)&Pl[(32 + lm) * V_STRIDE + kb2 * 16 + lh * 8];
            f16x8 va0 = *(const f16x8*)&Vs[(w * 64 + lm) * V_STRIDE + kb2 * 16 + lh * 8];
            f16x8 va1 = *(const f16x8*)&Vs[(w * 64 + 32 + lm) * V_STRIDE + kb2 * 16 + lh * 8];
            facc[0] = __builtin_amdgcn_mfma_f32_32x32x16_f16(va0, pf0, facc[0], 0, 0, 0);
            facc[1] = __builtin_amdgcn_mfma_f32_32x32x16_f16(va0, pf1, facc[1], 0, 0, 0);
            facc[2] = __builtin_amdgcn_mfma_f32_32x32x16_f16(va1, pf0, facc[2], 0, 0, 0);
            facc[3] = __builtin_amdgcn_mfma_f32_32x32x16_f16(va1, pf1, facc[3], 0, 0, 0);
        }
        __builtin_amdgcn_s_setprio(0);
    }

    // partial F out: Fp[bq][half][c][p] fp32
    float* dst = Fp + ((size_t)bq * 2 + half) * (CDIM * 64);
    #pragma unroll
    for (int ii = 0; ii < 2; ++ii)
        #pragma unroll
        for (int jj = 0; jj < 2; ++jj)
            #pragma unroll
            for (int r = 0; r < 16; ++r) {
                int c = w * 64 + ii * 32 + (r & 3) + 8 * (r >> 2) + 4 * lh;
                int p = jj * 32 + lm;
                dst[c * 64 + p] = facc[ii * 2 + jj][r];
            }
}

// ---------------------------------------------------------------------------
// merge_ln: grid 256 = (b<<6 | qtile), 256 thr. Sums the 2 half-partials
// into LDS, computes per-position mean/var over channels, writes normalized
// output. (unchanged, proven correct)
// ---------------------------------------------------------------------------
__global__ __launch_bounds__(256, 2) void merge_ln_kernel(
    const float* __restrict__ Fp, const float* __restrict__ ln_w,
    const float* __restrict__ ln_b, float* __restrict__ out)
{
    __shared__ float Fs[256 * F_STRIDE];          // 69632 B
    __shared__ float redS[16 * 64], redQ[16 * 64];
    __shared__ float lnw_s[256], lnb_s[256];
    __shared__ float mu_s[64], rs_s[64];

    const int t  = threadIdx.x;
    const int bq = blockIdx.x;
    const int b  = bq >> 6;
    const int p0 = (bq & 63) << 6;

    lnw_s[t] = ln_w[t]; lnb_s[t] = ln_b[t];

    const int pb = (t & 15) * 4;      // 4 consecutive positions
    const int cg = t >> 4;            // 16-channel group
    const float* base = Fp + (size_t)bq * 2 * (CDIM * 64);

    f32x4 s4 = {}, q4 = {};
    #pragma unroll 4
    for (int ci = 0; ci < 16; ++ci) {
        int c = cg * 16 + ci;
        size_t off = (size_t)c * 64 + pb;
        f32x4 v = *(const f32x4*)(base + off);
        v += *(const f32x4*)(base + (size_t)(CDIM * 64) + off);
        *(f32x4*)&Fs[c * F_STRIDE + pb] = v;
        s4 += v; q4 += v * v;
    }
    #pragma unroll
    for (int k2 = 0; k2 < 4; ++k2) {
        redS[cg * 64 + pb + k2] = s4[k2];
        redQ[cg * 64 + pb + k2] = q4[k2];
    }
    __syncthreads();
    if (t < 64) {
        float ss = 0.f, qq = 0.f;
        #pragma unroll
        for (int g2 = 0; g2 < 16; ++g2) { ss += redS[g2 * 64 + t]; qq += redQ[g2 * 64 + t]; }
        float mean = ss * (1.0f / 256.0f);
        float var  = qq * (1.0f / 256.0f) - mean * mean;
        mu_s[t] = mean;
        rs_s[t] = rsqrtf(var + EPSV);
    }
    __syncthreads();
    const int p   = t & 63;
    const int cg2 = t >> 6;
    const float mu = mu_s[p], rs = rs_s[p];
    float* dst = out + (size_t)b * CDIM * NPOS + p0 + p;
    #pragma unroll 4
    for (int ci = 0; ci < 64; ++ci) {
        int c = cg2 * 64 + ci;
        dst[(size_t)c * NPOS] = (Fs[c * F_STRIDE + p] - mu) * rs * lnw_s[c] + lnb_s[c];
    }
}

// ---------------------------------------------------------------------------
extern "C" void kernel_launch(void* const* d_in, const int* in_sizes, int n_in,
                              void* d_out, int out_size, void* d_ws, size_t ws_size,
                              hipStream_t stream)
{
    const float* x1  = (const float*)d_in[0];
    const float* x2  = (const float*)d_in[1];
    const float* qw  = (const float*)d_in[2];
    const float* qb  = (const float*)d_in[3];
    const float* kw  = (const float*)d_in[4];
    const float* kb  = (const float*)d_in[5];
    const float* vw  = (const float*)d_in[6];
    const float* vb  = (const float*)d_in[7];
    const float* lnw = (const float*)d_in[8];
    const float* lnb = (const float*)d_in[9];

    const size_t tsz = (size_t)BATCH * NPOS * CDIM;
    f16* Qg  = (f16*)d_ws;
    f16* Kg  = Qg + tsz;
    f16* Vg  = Kg + tsz;
    f16* Wf  = Vg + tsz;                          // 384 KB fragment-major W
    float* Fp = (float*)(Wf + 3 * CDIM * CDIM);   // 32 MB fp32; total ws ~57 MB

    wconv_kernel<<<24, 256, 0, stream>>>(qw, kw, vw, Wf);
    gemm_kernel<<<512, 256, 0, stream>>>(x1, x2, Wf, qb, kb, vb, Qg, Kg, Vg);
    attn_kernel<<<512, 256, 0, stream>>>(Qg, Kg, Vg, Fp);
    merge_ln_kernel<<<256, 256, 0, stream>>>(Fp, lnw, lnb, (float*)d_out);
}

// Round 14
// 227.452 us; speedup vs baseline: 1.0663x; 1.0663x over previous
//
#include <hip/hip_runtime.h>

// B=4, C=256, H=W=64 (N=4096). QKV 1x1conv -> spatial attention (softmax over
// j only => independent per-64-key-chunk softmax) -> channel LayerNorm.
// f16 MFMA 32x32x16, fp32 accumulation.
//
// R20: R18 base (attn main loop = R16 verbatim; frag-major gemm; wconv) with
// merge_ln FUSED into attn via a paired-block handshake. The two half-blocks
// of each (b,qtile) are co-resident (512 blocks = 2/CU exact) and ADJACENT
// bids (bid = qt*8+grp) -> deadlock-safe flag spin. Producer (half != qt&1):
// write 64KB partial -> threadfence -> release flag. Consumer: acquire-spin,
// read partner tile, merge in regs, run R6's proven fused-LN epilogue (LN
// scratch aliased into dead Ks; LDS stays 80896B). Post-attn traffic 80MB ->
// 48MB, one fewer launch. wconv zeroes flags each launch (graph-replay safe).
// R19's KV-merge gemm reverted (load imbalance: -30us).

#define CDIM 256
#define NPOS 4096
#define BATCH 4
#define EPSV 1e-5f

typedef _Float16 f16;
typedef __attribute__((ext_vector_type(4))) _Float16 f16x4;
typedef __attribute__((ext_vector_type(8))) _Float16 f16x8;
typedef __attribute__((ext_vector_type(4))) float f32x4;
typedef __attribute__((ext_vector_type(16))) float f32x16;

#define WST       264   // f16; 528B = 33*16 -> b128-aligned rows
#define QK_STRIDE 264   // f16 K-tile rows
#define V_STRIDE  72    // f16 Vs/P rows; 144B = 9*16
#define DQ_STRIDE 72

// LDS-only barrier: prior LDS ops complete, global loads stay in flight.
#define LBAR() asm volatile("s_waitcnt lgkmcnt(0)\n\ts_barrier" ::: "memory")

// MFMA 32x32x16 f16:
//   A: lane l holds A[m=l&31][k=(l>>5)*8+j]
//   B: lane l holds B[k=(l>>5)*8+j][n=l&31]   (same register layout as A)
//   C/D: lane l, reg r -> row m=(r&3)+8*(r>>2)+4*(l>>5), col n=l&31
//
// Fragment-major W: Wf[(pr*8 + q*2 + ot)*8192 + (ks*64 + lane)*8], lane l
// covering W[o = q*64 + ot*32 + (l&31)][c = ks*16 + (l>>5)*8 + 0..7].

static __device__ __forceinline__ f16x8 cvt8(const float* __restrict__ p) {
    float4 w0 = *(const float4*)p;
    float4 w1 = *(const float4*)(p + 4);
    f16x8 r;
    r[0] = (f16)w0.x; r[1] = (f16)w0.y; r[2] = (f16)w0.z; r[3] = (f16)w0.w;
    r[4] = (f16)w1.x; r[5] = (f16)w1.y; r[6] = (f16)w1.z; r[7] = (f16)w1.w;
    return r;
}

// ---------------------------------------------------------------------------
// wconv: 24 blocks = pr*8 + q*2 + ot. fp32 weights -> fragment-major f16 Wf.
// Block 0 also zeroes the 256 handshake flags (runs before attn every launch).
// ---------------------------------------------------------------------------
__global__ __launch_bounds__(256, 4) void wconv_kernel(
    const float* __restrict__ qw, const float* __restrict__ kw,
    const float* __restrict__ vw, f16* __restrict__ Wf, int* __restrict__ flags)
{
    const int id = blockIdx.x;           // 0..23
    const int t  = threadIdx.x;
    if (id == 0) flags[t] = 0;
    const int pr = id >> 3;
    const int q  = (id >> 1) & 3;
    const int ot = id & 1;
    const float* W = (pr == 0 ? qw : pr == 1 ? kw : vw);
    f16* D = Wf + (size_t)id * 8192;
    #pragma unroll
    for (int i = 0; i < 4; ++i) {
        int idx = t + i * 256;           // 0..1023 = ks*64 + l
        int ks = idx >> 6, l = idx & 63;
        const float* src = W + (size_t)(q * 64 + ot * 32 + (l & 31)) * CDIM
                             + ks * 16 + (l >> 5) * 8;
        *(f16x8*)(D + (size_t)idx * 8) = cvt8(src);
    }
}

// ---------------------------------------------------------------------------
// gemm: R18 verbatim. 768 blocks = (pr, b, ptile), (256,3) -> 3 blocks/CU,
// one pass. Xs staged from fp32 x (transpose in staging); W fragments direct
// from fragment-major global, prefetched one q-round ahead.
// ---------------------------------------------------------------------------
__global__ __launch_bounds__(256, 3) void gemm_kernel(
    const float* __restrict__ x1, const float* __restrict__ x2,
    const f16* __restrict__ Wf,
    const float* __restrict__ qb, const float* __restrict__ kb,
    const float* __restrict__ vb,
    f16* __restrict__ Qg, f16* __restrict__ Kg, f16* __restrict__ Vg)
{
    __shared__ f16 Xs[64 * WST];          // 33792 B
    __shared__ f16 Ds[64 * DQ_STRIDE];    //  9216 B
    __shared__ float biasS[256];          //  1024 B   (total 44032 B)

    const int id = blockIdx.x;
    const int pr  = id >> 8;
    const int rem = id & 255;
    const int b   = rem >> 6;
    const int p0  = (rem & 63) << 6;
    const float* xsrc = ((pr == 0) ? x1 : x2) + (size_t)b * CDIM * NPOS + p0;
    const float* bias = (pr == 0) ? qb : (pr == 1) ? kb : vb;

    const int t = threadIdx.x, w = t >> 6, l = t & 63, lm = l & 31, lh = l >> 5;
    const int pt = w & 1, ot = w >> 1;

    const f16* Wfp = Wf + (size_t)pr * 65536 + (size_t)ot * 8192;

    biasS[t] = bias[t];
    // Xs[p][c] <- x[b][c][p0+p], fp32->f16 (transpose via staging, proven)
    #pragma unroll
    for (int g = 0; g < 8; ++g) {
        f16x8 h;
        #pragma unroll
        for (int j = 0; j < 8; ++j)
            h[j] = (f16)xsrc[(size_t)(w * 64 + g * 8 + j) * NPOS + l];
        *(f16x8*)&Xs[l * WST + w * 64 + g * 8] = h;
    }

    // q=0 W fragments (each: 64 lanes x 16B = 1KB contiguous per instr)
    f16x8 wf[16];
    #pragma unroll
    for (int ks = 0; ks < 16; ++ks)
        wf[ks] = *(const f16x8*)(Wfp + (size_t)ks * 512 + l * 8);

    __syncthreads();   // Xs ready

    for (int q = 0; q < 4; ++q) {
        f32x16 accA = {}, accB = {};
        #pragma unroll
        for (int ks = 0; ks < 16; ks += 2) {
            f16x8 x0  = *(const f16x8*)&Xs[(pt * 32 + lm) * WST + ks * 16 + lh * 8];
            f16x8 x1v = *(const f16x8*)&Xs[(pt * 32 + lm) * WST + (ks + 1) * 16 + lh * 8];
            if (pr < 2) {
                accA = __builtin_amdgcn_mfma_f32_32x32x16_f16(x0, wf[ks], accA, 0, 0, 0);
                accB = __builtin_amdgcn_mfma_f32_32x32x16_f16(x1v, wf[ks + 1], accB, 0, 0, 0);
            } else {
                accA = __builtin_amdgcn_mfma_f32_32x32x16_f16(wf[ks], x0, accA, 0, 0, 0);
                accB = __builtin_amdgcn_mfma_f32_32x32x16_f16(wf[ks + 1], x1v, accB, 0, 0, 0);
            }
        }

        // prefetch next round's W fragments (overlap Ds + store phases)
        if (q < 3) {
            #pragma unroll
            for (int ks = 0; ks < 16; ++ks)
                wf[ks] = *(const f16x8*)(Wfp + (size_t)(q + 1) * 16384
                                             + (size_t)ks * 512 + l * 8);
        }

        if (pr < 2) {
            int o_l = ot * 32 + lm;
            float bv = biasS[q * 64 + o_l];
            #pragma unroll
            for (int r = 0; r < 16; ++r) {
                int p_l = pt * 32 + (r & 3) + 8 * (r >> 2) + 4 * lh;
                Ds[p_l * DQ_STRIDE + o_l] = (f16)(accA[r] + accB[r] + bv);
            }
        } else {
            #pragma unroll
            for (int r = 0; r < 16; ++r) {
                int o_l = ot * 32 + (r & 3) + 8 * (r >> 2) + 4 * lh;
                Ds[o_l * DQ_STRIDE + pt * 32 + lm] =
                    (f16)(accA[r] + accB[r] + biasS[q * 64 + o_l]);
            }
        }
        LBAR();

        #pragma unroll
        for (int j = 0; j < 2; ++j) {
            int row = (t >> 3) + j * 32;
            int cc  = (t & 7) * 8;
            f16x8 vdat = *(const f16x8*)&Ds[row * DQ_STRIDE + cc];
            if (pr < 2) {
                f16* Out = (pr == 0) ? Qg : Kg;
                *(f16x8*)(Out + ((size_t)(b * NPOS + p0 + row)) * CDIM + q * 64 + cc) = vdat;
            } else {
                *(f16x8*)(Vg + ((size_t)(b * CDIM + q * 64 + row)) * NPOS + p0 + cc) = vdat;
            }
        }
        LBAR();
    }
}

// ---------------------------------------------------------------------------
// attn: main loop = R16 verbatim (proven 105.9us x3). Epilogue: paired-block
// handshake. Producer writes 64KB partial -> fence -> release flag. Consumer
// (half == qt&1) acquire-spins (partner is co-resident, ADJACENT bid), reads
// partner tile, merges in regs, fused LN (R6's proven epilogue; scratch
// aliased into dead Ks). LDS 80896 B unchanged -> 2 blocks/CU.
// ---------------------------------------------------------------------------
__global__ __launch_bounds__(256, 2) void attn_kernel(
    const f16* __restrict__ Qg, const f16* __restrict__ Kg, const f16* __restrict__ Vg,
    const float* __restrict__ ln_w, const float* __restrict__ ln_b,
    float* __restrict__ Fp, int* __restrict__ flags, float* __restrict__ out)
{
    __shared__ f16   Ks[64 * QK_STRIDE];   // 33792 B  [key][c] (epilogue: LN scratch)
    __shared__ f16   Vs[256 * V_STRIDE];   // 36864 B  [c][j]
    __shared__ f16   Pl[64 * V_STRIDE];    //  9216 B  [p][key]
    __shared__ float RedM[2][64], RedS[2][64];  // 1024 B

    const int t    = threadIdx.x;
    const int L    = (int)((blockIdx.x & 7) * 64 + (blockIdx.x >> 3)); // XCD swizzle
    const int grp  = L >> 6;         // 0..7 = (b<<1 | half)
    const int b    = grp >> 1;
    const int half = grp & 1;
    const int qt   = L & 63;
    const int p0   = qt << 6;
    const int bq   = b * 64 + qt;
    const int w    = t >> 6;         // 0..3
    const int l    = t & 63;
    const int lm   = l & 31;
    const int lh   = l >> 5;
    const int spt  = w & 1;          // wave's p-tile
    const int skt  = w >> 1;         // wave's key-tile

    // Q fragments (MFMA B-operand; layout identical to A-operand)
    f16x8 qf[16];
    {
        const f16* qptr = Qg + (size_t)(b * NPOS + p0 + spt * 32 + lm) * CDIM + lh * 8;
        #pragma unroll
        for (int ks = 0; ks < 16; ++ks) qf[ks] = *(const f16x8*)(qptr + ks * 16);
    }

    // K prefetch registers (rows coalesced from Kg[n][c])
    const int kr = t >> 5, koff = (t & 31) * 8;
    f16x8 kreg[8];
    auto issue_k = [&](int ch) {
        const int i0 = ch * 64;
        #pragma unroll
        for (int r = 0; r < 8; ++r)
            kreg[r] = *(const f16x8*)(Kg + (size_t)(b * NPOS + i0 + r * 8 + kr) * CDIM + koff);
    };

    // V prefetch registers (128B-contiguous runs per c-row from Vg[c][n])
    const int vr = t >> 3;           // c row within each 32-row group
    const int vc = (t & 7) * 8;      // halfword col within chunk
    f16x8 vreg[8];
    auto issue_v = [&](int ch) {
        const int i0 = ch * 64;
        #pragma unroll
        for (int i = 0; i < 8; ++i)
            vreg[i] = *(const f16x8*)(Vg + (size_t)(b * CDIM + i * 32 + vr) * NPOS + i0 + vc);
    };

    issue_k(half * 32);
    issue_v(half * 32);

    f32x16 facc[4] = {};      // per-wave F acc: [ci=c-subtile(2)][pj=p-tile(2)]

    for (int it = 0; it < 32; ++it) {
        const int ch = half * 32 + it;

        // commit prefetched K to LDS, then issue next chunk's K loads
        #pragma unroll
        for (int r = 0; r < 8; ++r)
            *(f16x8*)&Ks[(r * 8 + kr) * QK_STRIDE + koff] = kreg[r];
        if (it < 31) issue_k(ch + 1);
        LBAR();   // A: Ks ready; prev PV's Vs/Pl reads done

        // commit prefetched V to LDS, then issue next chunk's V loads
        #pragma unroll
        for (int i = 0; i < 8; ++i)
            *(f16x8*)&Vs[(i * 32 + vr) * V_STRIDE + vc] = vreg[i];
        if (it < 31) issue_v(ch + 1);

        // S^T = K Q^T : D[m=key][n=p]; lane holds S^T[16 keys][p=spt*32+lm]
        f32x16 st = {};
        __builtin_amdgcn_s_setprio(1);
        #pragma unroll
        for (int ks = 0; ks < 16; ++ks) {
            f16x8 kf = *(const f16x8*)&Ks[(skt * 32 + lm) * QK_STRIDE + ks * 16 + lh * 8];
            st = __builtin_amdgcn_mfma_f32_32x32x16_f16(kf, qf[ks], st, 0, 0, 0);
        }
        __builtin_amdgcn_s_setprio(0);

        // in-register softmax over this key-tile (32 keys: 16 own + lh-partner)
        float mx = st[0];
        #pragma unroll
        for (int r = 1; r < 16; ++r) mx = fmaxf(mx, st[r]);
        mx = fmaxf(mx, __shfl_xor(mx, 32));
        float ss = 0.f;
        #pragma unroll
        for (int r = 0; r < 16; ++r) {
            float e = __expf(st[r] - mx);
            st[r] = e;
            ss += e;
        }
        ss += __shfl_xor(ss, 32);
        if (lh == 0) { RedM[skt][spt * 32 + lm] = mx; RedS[skt][spt * 32 + lm] = ss; }
        LBAR();   // B: Red exchange ready

        // LSE merge with partner key-tile wave -> full 64-key softmax
        float mo = RedM[skt ^ 1][spt * 32 + lm];
        float so = RedS[skt ^ 1][spt * 32 + lm];
        float M  = fmaxf(mx, mo);
        float S  = ss * __expf(mx - M) + so * __expf(mo - M);
        float scale = __expf(mx - M) * __builtin_amdgcn_rcpf(S);

        // P[key][p] f16 -> Pl[p][key]; lane's 16 keys = 4 runs of 4 consecutive
        #pragma unroll
        for (int rq = 0; rq < 4; ++rq) {
            f16x4 pk;
            #pragma unroll
            for (int q2 = 0; q2 < 4; ++q2) pk[q2] = (f16)(st[rq * 4 + q2] * scale);
            *(f16x4*)&Pl[(spt * 32 + lm) * V_STRIDE + skt * 32 + rq * 8 + lh * 4] = pk;
        }
        LBAR();   // C: Pl ready; Vs commits drained

        // F += V P : D[m=c][n=p]; A=Vs rows, B=Pl rows (both b128-contiguous)
        __builtin_amdgcn_s_setprio(1);
        #pragma unroll
        for (int kb = 0; kb < 4; ++kb) {
            f16x8 pf0 = *(const f16x8*)&Pl[lm * V_STRIDE + kb * 16 + lh * 8];
            f16x8 pf1 = *(const f16x8*)&Pl[(32 + lm) * V_STRIDE + kb * 16 + lh * 8];
            f16x8 va0 = *(const f16x8*)&Vs[(w * 64 + lm) * V_STRIDE + kb * 16 + lh * 8];
            f16x8 va1 = *(const f16x8*)&Vs[(w * 64 + 32 + lm) * V_STRIDE + kb * 16 + lh * 8];
            facc[0] = __builtin_amdgcn_mfma_f32_32x32x16_f16(va0, pf0, facc[0], 0, 0, 0);
            facc[1] = __builtin_amdgcn_mfma_f32_32x32x16_f16(va0, pf1, facc[1], 0, 0, 0);
            facc[2] = __builtin_amdgcn_mfma_f32_32x32x16_f16(va1, pf0, facc[2], 0, 0, 0);
            facc[3] = __builtin_amdgcn_mfma_f32_32x32x16_f16(va1, pf1, facc[3], 0, 0, 0);
        }
        __builtin_amdgcn_s_setprio(0);
    }

    // ---- paired-block merge + fused LayerNorm ----
    int* flag = flags + bq;
    const int isCons = (half == (qt & 1));

    if (!isCons) {
        // producer: write partial tile, fence, release flag
        float* dst = Fp + (size_t)bq * (CDIM * 64);
        #pragma unroll
        for (int ii = 0; ii < 2; ++ii)
            #pragma unroll
            for (int jj = 0; jj < 2; ++jj)
                #pragma unroll
                for (int r = 0; r < 16; ++r) {
                    int c = w * 64 + ii * 32 + (r & 3) + 8 * (r >> 2) + 4 * lh;
                    int p = jj * 32 + lm;
                    dst[c * 64 + p] = facc[ii * 2 + jj][r];
                }
        __syncthreads();   // all threads' writes issued + drained (vmcnt 0)
        if (t == 0) {
            __threadfence();
            __hip_atomic_store(flag, 1, __ATOMIC_RELEASE, __HIP_MEMORY_SCOPE_AGENT);
        }
        return;
    }

    // consumer: spin for partner (co-resident, adjacent bid -> no deadlock)
    if (t == 0) {
        while (__hip_atomic_load(flag, __ATOMIC_ACQUIRE, __HIP_MEMORY_SCOPE_AGENT) == 0)
            __builtin_amdgcn_s_sleep(2);
    }
    __syncthreads();

    // merge partner tile into registers
    {
        const float* src = Fp + (size_t)bq * (CDIM * 64);
        #pragma unroll
        for (int ii = 0; ii < 2; ++ii)
            #pragma unroll
            for (int jj = 0; jj < 2; ++jj)
                #pragma unroll
                for (int r = 0; r < 16; ++r) {
                    int c = w * 64 + ii * 32 + (r & 3) + 8 * (r >> 2) + 4 * lh;
                    int p = jj * 32 + lm;
                    facc[ii * 2 + jj][r] += src[c * 64 + p];
                }
    }

    // fused LN (R6's proven epilogue); scratch aliased into dead Ks
    float* scr   = (float*)&Ks[0];
    float* lnS   = scr;          // 256
    float* lnQ   = scr + 256;    // 256
    float* mu_s  = scr + 512;    // 64
    float* rs_s  = scr + 576;    // 64
    float* lnw_s = scr + 640;    // 256
    float* lnb_s = scr + 896;    // 256

    lnw_s[t] = ln_w[t];
    lnb_s[t] = ln_b[t];

    float ps0 = 0.f, pq0 = 0.f, ps1 = 0.f, pq1 = 0.f;
    #pragma unroll
    for (int ii = 0; ii < 2; ++ii)
        #pragma unroll
        for (int r = 0; r < 16; ++r) {
            float a  = facc[ii * 2 + 0][r];
            float c2 = facc[ii * 2 + 1][r];
            ps0 += a;  pq0 += a * a;
            ps1 += c2; pq1 += c2 * c2;
        }
    ps0 += __shfl_xor(ps0, 32); pq0 += __shfl_xor(pq0, 32);
    ps1 += __shfl_xor(ps1, 32); pq1 += __shfl_xor(pq1, 32);
    if (lh == 0) {
        lnS[w * 64 + lm] = ps0;       lnQ[w * 64 + lm] = pq0;
        lnS[w * 64 + 32 + lm] = ps1;  lnQ[w * 64 + 32 + lm] = pq1;
    }
    __syncthreads();
    if (t < 64) {
        float ssum = lnS[t] + lnS[64 + t] + lnS[128 + t] + lnS[192 + t];
        float qsum = lnQ[t] + lnQ[64 + t] + lnQ[128 + t] + lnQ[192 + t];
        float mean = ssum * (1.0f / 256.0f);
        float var  = qsum * (1.0f / 256.0f) - mean * mean;
        mu_s[t] = mean;
        rs_s[t] = rsqrtf(var + EPSV);
    }
    __syncthreads();

    float* o0 = out + (size_t)b * CDIM * NPOS + p0;
    #pragma unroll
    for (int ii = 0; ii < 2; ++ii)
        #pragma unroll
        for (int jj = 0; jj < 2; ++jj) {
            int p = jj * 32 + lm;
            float mu = mu_s[p], rs = rs_s[p];
            #pragma unroll
            for (int r = 0; r < 16; ++r) {
                int c = w * 64 + ii * 32 + (r & 3) + 8 * (r >> 2) + 4 * lh;
                o0[(size_t)c * NPOS + p] =
                    (facc[ii * 2 + jj][r] - mu) * rs * lnw_s[c] + lnb_s[c];
            }
        }
}

// ---------------------------------------------------------------------------
extern "C" void kernel_launch(void* const* d_in, const int* in_sizes, int n_in,
                              void* d_out, int out_size, void* d_ws, size_t ws_size,
                              hipStream_t stream)
{
    const float* x1  = (const float*)d_in[0];
    const float* x2  = (const float*)d_in[1];
    const float* qw  = (const float*)d_in[2];
    const float* qb  = (const float*)d_in[3];
    const float* kw  = (const float*)d_in[4];
    const float* kb  = (const float*)d_in[5];
    const float* vw  = (const float*)d_in[6];
    const float* vb  = (const float*)d_in[7];
    const float* lnw = (const float*)d_in[8];
    const float* lnb = (const float*)d_in[9];

    const size_t tsz = (size_t)BATCH * NPOS * CDIM;
    f16* Qg  = (f16*)d_ws;
    f16* Kg  = Qg + tsz;
    f16* Vg  = Kg + tsz;
    f16* Wf  = Vg + tsz;                          // 384 KB fragment-major W
    float* Fp = (float*)(Wf + 3 * CDIM * CDIM);   // 16 MB fp32 partials
    int* flags = (int*)(Fp + (size_t)256 * CDIM * 64);  // 256 handshake flags

    wconv_kernel<<<24, 256, 0, stream>>>(qw, kw, vw, Wf, flags);
    gemm_kernel<<<768, 256, 0, stream>>>(x1, x2, Wf, qb, kb, vb, Qg, Kg, Vg);
    attn_kernel<<<512, 256, 0, stream>>>(Qg, Kg, Vg, lnw, lnb, Fp, flags,
                                         (float*)d_out);
}

// Round 15
// 208.414 us; speedup vs baseline: 1.1637x; 1.0913x over previous
//
#include <hip/hip_runtime.h>

// B=4, C=256, H=W=64 (N=4096). QKV 1x1conv -> spatial attention (softmax over
// j only => independent per-64-key-chunk softmax) -> channel LayerNorm.
// f16 MFMA 32x32x16, fp32 accumulation.
//
// R21: revert R20's fused handshake (+25us in attn: consumer spin + fence +
// cross-XCD first-touch reads serialized what independent blocks overlap).
// Base = R18 (best stable, 210.9us): attn R16 verbatim, frag-major gemm
// (256,3), wconv. One low-risk change: merge_ln split 256 -> 512 blocks
// (32 positions each, LDS 69.6KB -> 47KB, 1 -> 2-3 blocks/CU) for latency
// hiding in the memory-bound merge. Channel-reduce per position unchanged.

#define CDIM 256
#define NPOS 4096
#define BATCH 4
#define EPSV 1e-5f

typedef _Float16 f16;
typedef __attribute__((ext_vector_type(4))) _Float16 f16x4;
typedef __attribute__((ext_vector_type(8))) _Float16 f16x8;
typedef __attribute__((ext_vector_type(4))) float f32x4;
typedef __attribute__((ext_vector_type(16))) float f32x16;

#define WST       264   // f16; 528B = 33*16 -> b128-aligned rows
#define QK_STRIDE 264   // f16 K-tile rows
#define V_STRIDE  72    // f16 Vs/P rows; 144B = 9*16
#define DQ_STRIDE 72
#define FM_STRIDE 36    // merge kernel LDS stride (f32, 32 pos + 4 pad)

// LDS-only barrier: prior LDS ops complete, global loads stay in flight.
#define LBAR() asm volatile("s_waitcnt lgkmcnt(0)\n\ts_barrier" ::: "memory")

// MFMA 32x32x16 f16:
//   A: lane l holds A[m=l&31][k=(l>>5)*8+j]
//   B: lane l holds B[k=(l>>5)*8+j][n=l&31]   (same register layout as A)
//   C/D: lane l, reg r -> row m=(r&3)+8*(r>>2)+4*(l>>5), col n=l&31
//
// Fragment-major W: Wf[(pr*8 + q*2 + ot)*8192 + (ks*64 + lane)*8], lane l
// covering W[o = q*64 + ot*32 + (l&31)][c = ks*16 + (l>>5)*8 + 0..7].

static __device__ __forceinline__ f16x8 cvt8(const float* __restrict__ p) {
    float4 w0 = *(const float4*)p;
    float4 w1 = *(const float4*)(p + 4);
    f16x8 r;
    r[0] = (f16)w0.x; r[1] = (f16)w0.y; r[2] = (f16)w0.z; r[3] = (f16)w0.w;
    r[4] = (f16)w1.x; r[5] = (f16)w1.y; r[6] = (f16)w1.z; r[7] = (f16)w1.w;
    return r;
}

// ---------------------------------------------------------------------------
// wconv: 24 blocks = pr*8 + q*2 + ot. fp32 weights -> fragment-major f16 Wf.
// ---------------------------------------------------------------------------
__global__ __launch_bounds__(256, 4) void wconv_kernel(
    const float* __restrict__ qw, const float* __restrict__ kw,
    const float* __restrict__ vw, f16* __restrict__ Wf)
{
    const int id = blockIdx.x;           // 0..23
    const int t  = threadIdx.x;
    const int pr = id >> 3;
    const int q  = (id >> 1) & 3;
    const int ot = id & 1;
    const float* W = (pr == 0 ? qw : pr == 1 ? kw : vw);
    f16* D = Wf + (size_t)id * 8192;
    #pragma unroll
    for (int i = 0; i < 4; ++i) {
        int idx = t + i * 256;           // 0..1023 = ks*64 + l
        int ks = idx >> 6, l = idx & 63;
        const float* src = W + (size_t)(q * 64 + ot * 32 + (l & 31)) * CDIM
                             + ks * 16 + (l >> 5) * 8;
        *(f16x8*)(D + (size_t)idx * 8) = cvt8(src);
    }
}

// ---------------------------------------------------------------------------
// gemm: R18 verbatim. 768 blocks = (pr, b, ptile), (256,3) -> 3 blocks/CU,
// one pass. Xs staged from fp32 x (transpose in staging); W fragments direct
// from fragment-major global, prefetched one q-round ahead.
// ---------------------------------------------------------------------------
__global__ __launch_bounds__(256, 3) void gemm_kernel(
    const float* __restrict__ x1, const float* __restrict__ x2,
    const f16* __restrict__ Wf,
    const float* __restrict__ qb, const float* __restrict__ kb,
    const float* __restrict__ vb,
    f16* __restrict__ Qg, f16* __restrict__ Kg, f16* __restrict__ Vg)
{
    __shared__ f16 Xs[64 * WST];          // 33792 B
    __shared__ f16 Ds[64 * DQ_STRIDE];    //  9216 B
    __shared__ float biasS[256];          //  1024 B   (total 44032 B)

    const int id = blockIdx.x;
    const int pr  = id >> 8;
    const int rem = id & 255;
    const int b   = rem >> 6;
    const int p0  = (rem & 63) << 6;
    const float* xsrc = ((pr == 0) ? x1 : x2) + (size_t)b * CDIM * NPOS + p0;
    const float* bias = (pr == 0) ? qb : (pr == 1) ? kb : vb;

    const int t = threadIdx.x, w = t >> 6, l = t & 63, lm = l & 31, lh = l >> 5;
    const int pt = w & 1, ot = w >> 1;

    const f16* Wfp = Wf + (size_t)pr * 65536 + (size_t)ot * 8192;

    biasS[t] = bias[t];
    // Xs[p][c] <- x[b][c][p0+p], fp32->f16 (transpose via staging, proven)
    #pragma unroll
    for (int g = 0; g < 8; ++g) {
        f16x8 h;
        #pragma unroll
        for (int j = 0; j < 8; ++j)
            h[j] = (f16)xsrc[(size_t)(w * 64 + g * 8 + j) * NPOS + l];
        *(f16x8*)&Xs[l * WST + w * 64 + g * 8] = h;
    }

    // q=0 W fragments (each: 64 lanes x 16B = 1KB contiguous per instr)
    f16x8 wf[16];
    #pragma unroll
    for (int ks = 0; ks < 16; ++ks)
        wf[ks] = *(const f16x8*)(Wfp + (size_t)ks * 512 + l * 8);

    __syncthreads();   // Xs ready

    for (int q = 0; q < 4; ++q) {
        f32x16 accA = {}, accB = {};
        #pragma unroll
        for (int ks = 0; ks < 16; ks += 2) {
            f16x8 x0  = *(const f16x8*)&Xs[(pt * 32 + lm) * WST + ks * 16 + lh * 8];
            f16x8 x1v = *(const f16x8*)&Xs[(pt * 32 + lm) * WST + (ks + 1) * 16 + lh * 8];
            if (pr < 2) {
                accA = __builtin_amdgcn_mfma_f32_32x32x16_f16(x0, wf[ks], accA, 0, 0, 0);
                accB = __builtin_amdgcn_mfma_f32_32x32x16_f16(x1v, wf[ks + 1], accB, 0, 0, 0);
            } else {
                accA = __builtin_amdgcn_mfma_f32_32x32x16_f16(wf[ks], x0, accA, 0, 0, 0);
                accB = __builtin_amdgcn_mfma_f32_32x32x16_f16(wf[ks + 1], x1v, accB, 0, 0, 0);
            }
        }

        // prefetch next round's W fragments (overlap Ds + store phases)
        if (q < 3) {
            #pragma unroll
            for (int ks = 0; ks < 16; ++ks)
                wf[ks] = *(const f16x8*)(Wfp + (size_t)(q + 1) * 16384
                                             + (size_t)ks * 512 + l * 8);
        }

        if (pr < 2) {
            int o_l = ot * 32 + lm;
            float bv = biasS[q * 64 + o_l];
            #pragma unroll
            for (int r = 0; r < 16; ++r) {
                int p_l = pt * 32 + (r & 3) + 8 * (r >> 2) + 4 * lh;
                Ds[p_l * DQ_STRIDE + o_l] = (f16)(accA[r] + accB[r] + bv);
            }
        } else {
            #pragma unroll
            for (int r = 0; r < 16; ++r) {
                int o_l = ot * 32 + (r & 3) + 8 * (r >> 2) + 4 * lh;
                Ds[o_l * DQ_STRIDE + pt * 32 + lm] =
                    (f16)(accA[r] + accB[r] + biasS[q * 64 + o_l]);
            }
        }
        LBAR();

        #pragma unroll
        for (int j = 0; j < 2; ++j) {
            int row = (t >> 3) + j * 32;
            int cc  = (t & 7) * 8;
            f16x8 vdat = *(const f16x8*)&Ds[row * DQ_STRIDE + cc];
            if (pr < 2) {
                f16* Out = (pr == 0) ? Qg : Kg;
                *(f16x8*)(Out + ((size_t)(b * NPOS + p0 + row)) * CDIM + q * 64 + cc) = vdat;
            } else {
                *(f16x8*)(Vg + ((size_t)(b * CDIM + q * 64 + row)) * NPOS + p0 + cc) = vdat;
            }
        }
        LBAR();
    }
}

// ---------------------------------------------------------------------------
// attn: R16 verbatim (proven 105.9us x3). grid 512, 256 thr = 4 waves,
// (256,2), 2 blocks/CU co-resident, bijective XCD swizzle. Per chunk: K+V
// reg-prefetch -> LDS commit; swapped QK^T (S^T in registers); in-register
// softmax with LSE cross-wave merge; P f16 tile -> LDS; PV from Vs+P
// ds_read_b128. 3 LDS-only barriers. Partial F fp32 [bq][half][256c][64p].
// ---------------------------------------------------------------------------
__global__ __launch_bounds__(256, 2) void attn_kernel(
    const f16* __restrict__ Qg, const f16* __restrict__ Kg, const f16* __restrict__ Vg,
    float* __restrict__ Fp)
{
    __shared__ f16   Ks[64 * QK_STRIDE];   // 33792 B  [key][c]
    __shared__ f16   Vs[256 * V_STRIDE];   // 36864 B  [c][j]
    __shared__ f16   Pl[64 * V_STRIDE];    //  9216 B  [p][key]
    __shared__ float RedM[2][64], RedS[2][64];  // 1024 B

    const int t    = threadIdx.x;
    const int L    = (int)((blockIdx.x & 7) * 64 + (blockIdx.x >> 3)); // XCD swizzle
    const int grp  = L >> 6;         // 0..7 = (b<<1 | half)
    const int b    = grp >> 1;
    const int half = grp & 1;
    const int qt   = L & 63;
    const int p0   = qt << 6;
    const int bq   = b * 64 + qt;
    const int w    = t >> 6;         // 0..3
    const int l    = t & 63;
    const int lm   = l & 31;
    const int lh   = l >> 5;
    const int spt  = w & 1;          // wave's p-tile
    const int skt  = w >> 1;         // wave's key-tile

    // Q fragments (MFMA B-operand; layout identical to A-operand)
    f16x8 qf[16];
    {
        const f16* qptr = Qg + (size_t)(b * NPOS + p0 + spt * 32 + lm) * CDIM + lh * 8;
        #pragma unroll
        for (int ks = 0; ks < 16; ++ks) qf[ks] = *(const f16x8*)(qptr + ks * 16);
    }

    // K prefetch registers (rows coalesced from Kg[n][c])
    const int kr = t >> 5, koff = (t & 31) * 8;
    f16x8 kreg[8];
    auto issue_k = [&](int ch) {
        const int i0 = ch * 64;
        #pragma unroll
        for (int r = 0; r < 8; ++r)
            kreg[r] = *(const f16x8*)(Kg + (size_t)(b * NPOS + i0 + r * 8 + kr) * CDIM + koff);
    };

    // V prefetch registers (128B-contiguous runs per c-row from Vg[c][n])
    const int vr = t >> 3;           // c row within each 32-row group
    const int vc = (t & 7) * 8;      // halfword col within chunk
    f16x8 vreg[8];
    auto issue_v = [&](int ch) {
        const int i0 = ch * 64;
        #pragma unroll
        for (int i = 0; i < 8; ++i)
            vreg[i] = *(const f16x8*)(Vg + (size_t)(b * CDIM + i * 32 + vr) * NPOS + i0 + vc);
    };

    issue_k(half * 32);
    issue_v(half * 32);

    f32x16 facc[4] = {};      // per-wave F acc: [ci=c-subtile(2)][pj=p-tile(2)]

    for (int it = 0; it < 32; ++it) {
        const int ch = half * 32 + it;

        // commit prefetched K to LDS, then issue next chunk's K loads
        #pragma unroll
        for (int r = 0; r < 8; ++r)
            *(f16x8*)&Ks[(r * 8 + kr) * QK_STRIDE + koff] = kreg[r];
        if (it < 31) issue_k(ch + 1);
        LBAR();   // A: Ks ready; prev PV's Vs/Pl reads done

        // commit prefetched V to LDS, then issue next chunk's V loads
        #pragma unroll
        for (int i = 0; i < 8; ++i)
            *(f16x8*)&Vs[(i * 32 + vr) * V_STRIDE + vc] = vreg[i];
        if (it < 31) issue_v(ch + 1);

        // S^T = K Q^T : D[m=key][n=p]; lane holds S^T[16 keys][p=spt*32+lm]
        f32x16 st = {};
        __builtin_amdgcn_s_setprio(1);
        #pragma unroll
        for (int ks = 0; ks < 16; ++ks) {
            f16x8 kf = *(const f16x8*)&Ks[(skt * 32 + lm) * QK_STRIDE + ks * 16 + lh * 8];
            st = __builtin_amdgcn_mfma_f32_32x32x16_f16(kf, qf[ks], st, 0, 0, 0);
        }
        __builtin_amdgcn_s_setprio(0);

        // in-register softmax over this key-tile (32 keys: 16 own + lh-partner)
        float mx = st[0];
        #pragma unroll
        for (int r = 1; r < 16; ++r) mx = fmaxf(mx, st[r]);
        mx = fmaxf(mx, __shfl_xor(mx, 32));
        float ss = 0.f;
        #pragma unroll
        for (int r = 0; r < 16; ++r) {
            float e = __expf(st[r] - mx);
            st[r] = e;
            ss += e;
        }
        ss += __shfl_xor(ss, 32);
        if (lh == 0) { RedM[skt][spt * 32 + lm] = mx; RedS[skt][spt * 32 + lm] = ss; }
        LBAR();   // B: Red exchange ready

        // LSE merge with partner key-tile wave -> full 64-key softmax
        float mo = RedM[skt ^ 1][spt * 32 + lm];
        float so = RedS[skt ^ 1][spt * 32 + lm];
        float M  = fmaxf(mx, mo);
        float S  = ss * __expf(mx - M) + so * __expf(mo - M);
        float scale = __expf(mx - M) * __builtin_amdgcn_rcpf(S);

        // P[key][p] f16 -> Pl[p][key]; lane's 16 keys = 4 runs of 4 consecutive
        #pragma unroll
        for (int rq = 0; rq < 4; ++rq) {
            f16x4 pk;
            #pragma unroll
            for (int q2 = 0; q2 < 4; ++q2) pk[q2] = (f16)(st[rq * 4 + q2] * scale);
            *(f16x4*)&Pl[(spt * 32 + lm) * V_STRIDE + skt * 32 + rq * 8 + lh * 4] = pk;
        }
        LBAR();   // C: Pl ready; Vs commits drained

        // F += V P : D[m=c][n=p]; A=Vs rows, B=Pl rows (both b128-contiguous)
        __builtin_amdgcn_s_setprio(1);
        #pragma unroll
        for (int kb = 0; kb < 4; ++kb) {
            f16x8 pf0 = *(const f16x8*)&Pl[lm * V_STRIDE + kb * 16 + lh * 8];
            f16x8 pf1 = *(const f16x8*)&Pl[(32 + lm) * V_STRIDE + kb * 16 + lh * 8];
            f16x8 va0 = *(const f16x8*)&Vs[(w * 64 + lm) * V_STRIDE + kb * 16 + lh * 8];
            f16x8 va1 = *(const f16x8*)&Vs[(w * 64 + 32 + lm) * V_STRIDE + kb * 16 + lh * 8];
            facc[0] = __builtin_amdgcn_mfma_f32_32x32x16_f16(va0, pf0, facc[0], 0, 0, 0);
            facc[1] = __builtin_amdgcn_mfma_f32_32x32x16_f16(va0, pf1, facc[1], 0, 0, 0);
            facc[2] = __builtin_amdgcn_mfma_f32_32x32x16_f16(va1, pf0, facc[2], 0, 0, 0);
            facc[3] = __builtin_amdgcn_mfma_f32_32x32x16_f16(va1, pf1, facc[3], 0, 0, 0);
        }
        __builtin_amdgcn_s_setprio(0);
    }

    // partial F out: Fp[bq][half][c][p] fp32
    float* dst = Fp + ((size_t)bq * 2 + half) * (CDIM * 64);
    #pragma unroll
    for (int ii = 0; ii < 2; ++ii)
        #pragma unroll
        for (int jj = 0; jj < 2; ++jj)
            #pragma unroll
            for (int r = 0; r < 16; ++r) {
                int c = w * 64 + ii * 32 + (r & 3) + 8 * (r >> 2) + 4 * lh;
                int p = jj * 32 + lm;
                dst[c * 64 + p] = facc[ii * 2 + jj][r];
            }
}

// ---------------------------------------------------------------------------
// merge_ln: grid 512 = (bq<<1 | poshalf), 256 thr, 32 positions per block.
// Sums the 2 half-partials into LDS, computes per-position mean/var over
// channels, writes normalized output. LDS 47KB -> 2-3 blocks/CU (was 1).
// ---------------------------------------------------------------------------
__global__ __launch_bounds__(256, 2) void merge_ln_kernel(
    const float* __restrict__ Fp, const float* __restrict__ ln_w,
    const float* __restrict__ ln_b, float* __restrict__ out)
{
    __shared__ float Fs[256 * FM_STRIDE];         // 36864 B
    __shared__ float redS[32 * 32], redQ[32 * 32]; // 8192 B
    __shared__ float lnw_s[256], lnb_s[256];
    __shared__ float mu_s[32], rs_s[32];

    const int t  = threadIdx.x;
    const int bq = blockIdx.x >> 1;
    const int ph = blockIdx.x & 1;
    const int b  = bq >> 6;
    const int p0 = (bq & 63) * 64 + ph * 32;

    lnw_s[t] = ln_w[t]; lnb_s[t] = ln_b[t];

    const int pb = (t & 7) * 4;       // 4 consecutive positions (of 32)
    const int cg = t >> 3;            // 32 groups x 8 channels
    const float* base = Fp + (size_t)bq * 2 * (CDIM * 64) + ph * 32;

    f32x4 s4 = {}, q4 = {};
    #pragma unroll
    for (int ci = 0; ci < 8; ++ci) {
        int c = cg * 8 + ci;
        size_t off = (size_t)c * 64 + pb;
        f32x4 v = *(const f32x4*)(base + off);
        v += *(const f32x4*)(base + (size_t)(CDIM * 64) + off);
        *(f32x4*)&Fs[c * FM_STRIDE + pb] = v;
        s4 += v; q4 += v * v;
    }
    #pragma unroll
    for (int k2 = 0; k2 < 4; ++k2) {
        redS[cg * 32 + pb + k2] = s4[k2];
        redQ[cg * 32 + pb + k2] = q4[k2];
    }
    __syncthreads();
    if (t < 32) {
        float ss = 0.f, qq = 0.f;
        #pragma unroll
        for (int g2 = 0; g2 < 32; ++g2) { ss += redS[g2 * 32 + t]; qq += redQ[g2 * 32 + t]; }
        float mean = ss * (1.0f / 256.0f);
        float var  = qq * (1.0f / 256.0f) - mean * mean;
        mu_s[t] = mean;
        rs_s[t] = rsqrtf(var + EPSV);
    }
    __syncthreads();
    const int p   = t & 31;
    const int cg2 = t >> 5;           // 8 groups x 32 channels
    const float mu = mu_s[p], rs = rs_s[p];
    float* dst = out + (size_t)b * CDIM * NPOS + p0 + p;
    #pragma unroll 4
    for (int ci = 0; ci < 32; ++ci) {
        int c = cg2 * 32 + ci;
        dst[(size_t)c * NPOS] = (Fs[c * FM_STRIDE + p] - mu) * rs * lnw_s[c] + lnb_s[c];
    }
}

// ---------------------------------------------------------------------------
extern "C" void kernel_launch(void* const* d_in, const int* in_sizes, int n_in,
                              void* d_out, int out_size, void* d_ws, size_t ws_size,
                              hipStream_t stream)
{
    const float* x1  = (const float*)d_in[0];
    const float* x2  = (const float*)d_in[1];
    const float* qw  = (const float*)d_in[2];
    const float* qb  = (const float*)d_in[3];
    const float* kw  = (const float*)d_in[4];
    const float* kb  = (const float*)d_in[5];
    const float* vw  = (const float*)d_in[6];
    const float* vb  = (const float*)d_in[7];
    const float* lnw = (const float*)d_in[8];
    const float* lnb = (const float*)d_in[9];

    const size_t tsz = (size_t)BATCH * NPOS * CDIM;
    f16* Qg  = (f16*)d_ws;
    f16* Kg  = Qg + tsz;
    f16* Vg  = Kg + tsz;
    f16* Wf  = Vg + tsz;                          // 384 KB fragment-major W
    float* Fp = (float*)(Wf + 3 * CDIM * CDIM);   // 32 MB fp32; total ws ~57 MB

    wconv_kernel<<<24, 256, 0, stream>>>(qw, kw, vw, Wf);
    gemm_kernel<<<768, 256, 0, stream>>>(x1, x2, Wf, qb, kb, vb, Qg, Kg, Vg);
    attn_kernel<<<512, 256, 0, stream>>>(Qg, Kg, Vg, Fp);
    merge_ln_kernel<<<512, 256, 0, stream>>>(Fp, lnw, lnb, (float*)d_out);
}

// Round 16
// 201.020 us; speedup vs baseline: 1.2065x; 1.0368x over previous
//
#include <hip/hip_runtime.h>

// B=4, C=256, H=W=64 (N=4096). QKV 1x1conv -> spatial attention (softmax over
// j only => independent per-64-key-chunk softmax) -> channel LayerNorm.
// f16 MFMA 32x32x16, fp32 accumulation.
//
// R22: attn in-loop cut, phase order preserved. (1) V read directly from
// FRAGMENT-MAJOR Vf (R12's harness-proven layout; 1KB-coalesced per-wave
// loads, latency hidden under QK+softmax) -> Vs LDS tile deleted. (2) Freed
// LDS pays for double-buffered Ks -> barrier A deleted (commit K(it+1) into
// the other buffer while QK reads current; races separated by B/C lgkm
// drains). Barriers 3->2 per chunk, LDS traffic/chunk -50%, LDS 80.9->77.8KB
// (still 2 blocks/CU). gemm: pr==2 epilogue emits Vf (R12's proven code);
// Q/K paths, wconv, merge_ln(512-block split), Fp layout: R21 verbatim.

#define CDIM 256
#define NPOS 4096
#define BATCH 4
#define EPSV 1e-5f

typedef _Float16 f16;
typedef __attribute__((ext_vector_type(4))) _Float16 f16x4;
typedef __attribute__((ext_vector_type(8))) _Float16 f16x8;
typedef __attribute__((ext_vector_type(4))) float f32x4;
typedef __attribute__((ext_vector_type(16))) float f32x16;

#define WST       264   // f16; 528B = 33*16 -> b128-aligned rows
#define QK_STRIDE 264   // f16 K-tile rows
#define V_STRIDE  72    // f16 P rows; 144B = 9*16
#define DQ_STRIDE 72
#define FM_STRIDE 36    // merge kernel LDS stride (f32, 32 pos + 4 pad)

// LDS-only barrier: prior LDS ops complete, global loads stay in flight.
#define LBAR() asm volatile("s_waitcnt lgkmcnt(0)\n\ts_barrier" ::: "memory")

// MFMA 32x32x16 f16:
//   A: lane l holds A[m=l&31][k=(l>>5)*8+j]
//   B: lane l holds B[k=(l>>5)*8+j][n=l&31]   (same register layout as A)
//   C/D: lane l, reg r -> row m=(r&3)+8*(r>>2)+4*(l>>5), col n=l&31
//
// Fragment-major W: Wf[(pr*8 + q*2 + ot)*8192 + (ks*64 + lane)*8], lane l
// covering W[o = q*64 + ot*32 + (l&31)][c = ks*16 + (l>>5)*8 + 0..7].
// Fragment-major V: Vf[b][ch(64)][ct(8)][kb(4)][lane(64)][8], lane l covering
// V[c = ct*32+(l&31)][j = ch*64 + kb*16+(l>>5)*8 + 0..7]  (R12-proven).

static __device__ __forceinline__ f16x8 cvt8(const float* __restrict__ p) {
    float4 w0 = *(const float4*)p;
    float4 w1 = *(const float4*)(p + 4);
    f16x8 r;
    r[0] = (f16)w0.x; r[1] = (f16)w0.y; r[2] = (f16)w0.z; r[3] = (f16)w0.w;
    r[4] = (f16)w1.x; r[5] = (f16)w1.y; r[6] = (f16)w1.z; r[7] = (f16)w1.w;
    return r;
}

// ---------------------------------------------------------------------------
// wconv: 24 blocks = pr*8 + q*2 + ot. fp32 weights -> fragment-major f16 Wf.
// ---------------------------------------------------------------------------
__global__ __launch_bounds__(256, 4) void wconv_kernel(
    const float* __restrict__ qw, const float* __restrict__ kw,
    const float* __restrict__ vw, f16* __restrict__ Wf)
{
    const int id = blockIdx.x;           // 0..23
    const int t  = threadIdx.x;
    const int pr = id >> 3;
    const int q  = (id >> 1) & 3;
    const int ot = id & 1;
    const float* W = (pr == 0 ? qw : pr == 1 ? kw : vw);
    f16* D = Wf + (size_t)id * 8192;
    #pragma unroll
    for (int i = 0; i < 4; ++i) {
        int idx = t + i * 256;           // 0..1023 = ks*64 + l
        int ks = idx >> 6, l = idx & 63;
        const float* src = W + (size_t)(q * 64 + ot * 32 + (l & 31)) * CDIM
                             + ks * 16 + (l >> 5) * 8;
        *(f16x8*)(D + (size_t)idx * 8) = cvt8(src);
    }
}

// ---------------------------------------------------------------------------
// gemm: R18/R21 structure. 768 blocks = (pr, b, ptile), (256,3). Xs staged
// from fp32 x; W fragments direct from fragment-major global, prefetched one
// q-round ahead. pr<2 stores row-major Q/K; pr==2 stores FRAGMENT-MAJOR Vf
// (R12's proven epilogue).
// ---------------------------------------------------------------------------
__global__ __launch_bounds__(256, 3) void gemm_kernel(
    const float* __restrict__ x1, const float* __restrict__ x2,
    const f16* __restrict__ Wf,
    const float* __restrict__ qb, const float* __restrict__ kb,
    const float* __restrict__ vb,
    f16* __restrict__ Qg, f16* __restrict__ Kg, f16* __restrict__ Vf)
{
    __shared__ f16 Xs[64 * WST];          // 33792 B
    __shared__ f16 Ds[64 * DQ_STRIDE];    //  9216 B
    __shared__ float biasS[256];          //  1024 B   (total 44032 B)

    const int id = blockIdx.x;
    const int pr  = id >> 8;
    const int rem = id & 255;
    const int b   = rem >> 6;
    const int p0  = (rem & 63) << 6;
    const float* xsrc = ((pr == 0) ? x1 : x2) + (size_t)b * CDIM * NPOS + p0;
    const float* bias = (pr == 0) ? qb : (pr == 1) ? kb : vb;

    const int t = threadIdx.x, w = t >> 6, l = t & 63, lm = l & 31, lh = l >> 5;
    const int pt = w & 1, ot = w >> 1;

    const f16* Wfp = Wf + (size_t)pr * 65536 + (size_t)ot * 8192;

    biasS[t] = bias[t];
    // Xs[p][c] <- x[b][c][p0+p], fp32->f16 (transpose via staging, proven)
    #pragma unroll
    for (int g = 0; g < 8; ++g) {
        f16x8 h;
        #pragma unroll
        for (int j = 0; j < 8; ++j)
            h[j] = (f16)xsrc[(size_t)(w * 64 + g * 8 + j) * NPOS + l];
        *(f16x8*)&Xs[l * WST + w * 64 + g * 8] = h;
    }

    // q=0 W fragments (each: 64 lanes x 16B = 1KB contiguous per instr)
    f16x8 wf[16];
    #pragma unroll
    for (int ks = 0; ks < 16; ++ks)
        wf[ks] = *(const f16x8*)(Wfp + (size_t)ks * 512 + l * 8);

    __syncthreads();   // Xs ready

    for (int q = 0; q < 4; ++q) {
        f32x16 accA = {}, accB = {};
        #pragma unroll
        for (int ks = 0; ks < 16; ks += 2) {
            f16x8 x0  = *(const f16x8*)&Xs[(pt * 32 + lm) * WST + ks * 16 + lh * 8];
            f16x8 x1v = *(const f16x8*)&Xs[(pt * 32 + lm) * WST + (ks + 1) * 16 + lh * 8];
            if (pr < 2) {
                accA = __builtin_amdgcn_mfma_f32_32x32x16_f16(x0, wf[ks], accA, 0, 0, 0);
                accB = __builtin_amdgcn_mfma_f32_32x32x16_f16(x1v, wf[ks + 1], accB, 0, 0, 0);
            } else {
                accA = __builtin_amdgcn_mfma_f32_32x32x16_f16(wf[ks], x0, accA, 0, 0, 0);
                accB = __builtin_amdgcn_mfma_f32_32x32x16_f16(wf[ks + 1], x1v, accB, 0, 0, 0);
            }
        }

        // prefetch next round's W fragments (overlap Ds + store phases)
        if (q < 3) {
            #pragma unroll
            for (int ks = 0; ks < 16; ++ks)
                wf[ks] = *(const f16x8*)(Wfp + (size_t)(q + 1) * 16384
                                             + (size_t)ks * 512 + l * 8);
        }

        if (pr < 2) {
            int o_l = ot * 32 + lm;
            float bv = biasS[q * 64 + o_l];
            #pragma unroll
            for (int r = 0; r < 16; ++r) {
                int p_l = pt * 32 + (r & 3) + 8 * (r >> 2) + 4 * lh;
                Ds[p_l * DQ_STRIDE + o_l] = (f16)(accA[r] + accB[r] + bv);
            }
        } else {
            #pragma unroll
            for (int r = 0; r < 16; ++r) {
                int o_l = ot * 32 + (r & 3) + 8 * (r >> 2) + 4 * lh;
                Ds[o_l * DQ_STRIDE + pt * 32 + lm] =
                    (f16)(accA[r] + accB[r] + biasS[q * 64 + o_l]);
            }
        }
        LBAR();

        if (pr < 2) {
            #pragma unroll
            for (int j = 0; j < 2; ++j) {
                int row = (t >> 3) + j * 32;
                int cc  = (t & 7) * 8;
                f16x8 vdat = *(const f16x8*)&Ds[row * DQ_STRIDE + cc];
                f16* Out = (pr == 0) ? Qg : Kg;
                *(f16x8*)(Out + ((size_t)(b * NPOS + p0 + row)) * CDIM + q * 64 + cc) = vdat;
            }
        } else {
            // V fragment-major (R12-proven): Ds[o][p] -> Vf[b][ch][q*2+ct][kb][lane][8]
            #pragma unroll
            for (int i = 0; i < 2; ++i) {
                int idx  = t + i * 256;
                int ct_l = idx >> 8;           // 0/1
                int kb_  = (idx >> 6) & 3;     // 0..3
                int l2   = idx & 63;
                f16x8 vdat = *(const f16x8*)&Ds[(ct_l * 32 + (l2 & 31)) * DQ_STRIDE +
                                                kb_ * 16 + (l2 >> 5) * 8];
                size_t fo = ((((size_t)b * 64 + (p0 >> 6)) * 8 + q * 2 + ct_l) * 4 + kb_) * 512
                            + l2 * 8;
                *(f16x8*)(Vf + fo) = vdat;
            }
        }
        LBAR();
    }
}

// ---------------------------------------------------------------------------
// attn: grid 512, 256 thr = 4 waves, (256,2), 2 blocks/CU, XCD swizzle.
// 2 LBARs/chunk: double-buffered Ks (commit K(it+1) into other buffer, no
// barrier needed before QK); V fragments direct from frag-major Vf (1KB
// coalesced, loaded at chunk top, consumed at PV). Swapped QK^T, in-register
// softmax + LSE merge, Pl single-buffer (race-audited: B/C drains suffice).
// LDS 77824 B. Emits partial F fp32 [bq][half][256c][64p].
// ---------------------------------------------------------------------------
__global__ __launch_bounds__(256, 2) void attn_kernel(
    const f16* __restrict__ Qg, const f16* __restrict__ Kg, const f16* __restrict__ Vf,
    float* __restrict__ Fp)
{
    __shared__ f16   Ks[2][64 * QK_STRIDE];     // 67584 B  [key][c] x2
    __shared__ f16   Pl[64 * V_STRIDE];         //  9216 B  [p][key]
    __shared__ float RedM[2][64], RedS[2][64];  //  1024 B

    const int t    = threadIdx.x;
    const int L    = (int)((blockIdx.x & 7) * 64 + (blockIdx.x >> 3)); // XCD swizzle
    const int grp  = L >> 6;         // 0..7 = (b<<1 | half)
    const int b    = grp >> 1;
    const int half = grp & 1;
    const int qt   = L & 63;
    const int p0   = qt << 6;
    const int bq   = b * 64 + qt;
    const int w    = t >> 6;         // 0..3
    const int l    = t & 63;
    const int lm   = l & 31;
    const int lh   = l >> 5;
    const int spt  = w & 1;          // wave's p-tile
    const int skt  = w >> 1;         // wave's key-tile

    // Q fragments (MFMA B-operand; layout identical to A-operand)
    f16x8 qf[16];
    {
        const f16* qptr = Qg + (size_t)(b * NPOS + p0 + spt * 32 + lm) * CDIM + lh * 8;
        #pragma unroll
        for (int ks = 0; ks < 16; ++ks) qf[ks] = *(const f16x8*)(qptr + ks * 16);
    }

    // K prefetch registers (rows coalesced from Kg[n][c])
    const int kr = t >> 5, koff = (t & 31) * 8;
    f16x8 kreg[8];
    auto issue_k = [&](int ch) {
        const int i0 = ch * 64;
        #pragma unroll
        for (int r = 0; r < 8; ++r)
            kreg[r] = *(const f16x8*)(Kg + (size_t)(b * NPOS + i0 + r * 8 + kr) * CDIM + koff);
    };

    const f16* Vfb = Vf + (size_t)b * 64 * 8 * 4 * 512;

    // prologue: K(c0) -> buf0; issue K(c0+1)
    issue_k(half * 32);
    #pragma unroll
    for (int r = 0; r < 8; ++r)
        *(f16x8*)&Ks[0][(r * 8 + kr) * QK_STRIDE + koff] = kreg[r];
    issue_k(half * 32 + 1);
    LBAR();   // buf0 ready

    f32x16 facc[4] = {};      // per-wave F acc: [ci=c-subtile(2)][pj=p-tile(2)]

    for (int it = 0; it < 32; ++it) {
        const int ch = half * 32 + it;
        const int cb = it & 1;

        // V fragments for this chunk (1KB coalesced; consumed at PV below --
        // latency hidden under K-commit + QK + softmax)
        const f16* Vt = Vfb + (size_t)ch * 8 * 4 * 512;
        f16x8 vf0[4], vf1[4];
        #pragma unroll
        for (int kb = 0; kb < 4; ++kb) {
            vf0[kb] = *(const f16x8*)(Vt + (size_t)((2 * w) * 4 + kb) * 512 + l * 8);
            vf1[kb] = *(const f16x8*)(Vt + (size_t)((2 * w + 1) * 4 + kb) * 512 + l * 8);
        }

        // commit prefetched K(it+1) into the OTHER buffer (prev reads of that
        // buffer finished before C(it-1)); issue K(it+2)
        if (it < 31) {
            #pragma unroll
            for (int r = 0; r < 8; ++r)
                *(f16x8*)&Ks[cb ^ 1][(r * 8 + kr) * QK_STRIDE + koff] = kreg[r];
            if (it < 30) issue_k(ch + 2);
        }

        // S^T = K Q^T from Ks[cb] (ready since last barrier pair)
        f32x16 st = {};
        __builtin_amdgcn_s_setprio(1);
        #pragma unroll
        for (int ks = 0; ks < 16; ++ks) {
            f16x8 kf = *(const f16x8*)&Ks[cb][(skt * 32 + lm) * QK_STRIDE + ks * 16 + lh * 8];
            st = __builtin_amdgcn_mfma_f32_32x32x16_f16(kf, qf[ks], st, 0, 0, 0);
        }
        __builtin_amdgcn_s_setprio(0);

        // in-register softmax over this key-tile (32 keys: 16 own + lh-partner)
        float mx = st[0];
        #pragma unroll
        for (int r = 1; r < 16; ++r) mx = fmaxf(mx, st[r]);
        mx = fmaxf(mx, __shfl_xor(mx, 32));
        float ss = 0.f;
        #pragma unroll
        for (int r = 0; r < 16; ++r) {
            float e = __expf(st[r] - mx);
            st[r] = e;
            ss += e;
        }
        ss += __shfl_xor(ss, 32);
        if (lh == 0) { RedM[skt][spt * 32 + lm] = mx; RedS[skt][spt * 32 + lm] = ss; }
        LBAR();   // B: Red ready; K-commit drained; all PV(it-1) Pl reads done

        // LSE merge with partner key-tile wave -> full 64-key softmax
        float mo = RedM[skt ^ 1][spt * 32 + lm];
        float so = RedS[skt ^ 1][spt * 32 + lm];
        float M  = fmaxf(mx, mo);
        float S  = ss * __expf(mx - M) + so * __expf(mo - M);
        float scale = __expf(mx - M) * __builtin_amdgcn_rcpf(S);

        // P[key][p] f16 -> Pl[p][key]
        #pragma unroll
        for (int rq = 0; rq < 4; ++rq) {
            f16x4 pk;
            #pragma unroll
            for (int q2 = 0; q2 < 4; ++q2) pk[q2] = (f16)(st[rq * 4 + q2] * scale);
            *(f16x4*)&Pl[(spt * 32 + lm) * V_STRIDE + skt * 32 + rq * 8 + lh * 4] = pk;
        }
        LBAR();   // C: Pl ready

        // F += V P : A = V fragments (regs, frag-major), B = Pl rows (b128)
        __builtin_amdgcn_s_setprio(1);
        #pragma unroll
        for (int kb = 0; kb < 4; ++kb) {
            f16x8 pf0 = *(const f16x8*)&Pl[lm * V_STRIDE + kb * 16 + lh * 8];
            f16x8 pf1 = *(const f16x8*)&Pl[(32 + lm) * V_STRIDE + kb * 16 + lh * 8];
            facc[0] = __builtin_amdgcn_mfma_f32_32x32x16_f16(vf0[kb], pf0, facc[0], 0, 0, 0);
            facc[1] = __builtin_amdgcn_mfma_f32_32x32x16_f16(vf0[kb], pf1, facc[1], 0, 0, 0);
            facc[2] = __builtin_amdgcn_mfma_f32_32x32x16_f16(vf1[kb], pf0, facc[2], 0, 0, 0);
            facc[3] = __builtin_amdgcn_mfma_f32_32x32x16_f16(vf1[kb], pf1, facc[3], 0, 0, 0);
        }
        __builtin_amdgcn_s_setprio(0);
    }

    // partial F out: Fp[bq][half][c][p] fp32
    float* dst = Fp + ((size_t)bq * 2 + half) * (CDIM * 64);
    #pragma unroll
    for (int ii = 0; ii < 2; ++ii)
        #pragma unroll
        for (int jj = 0; jj < 2; ++jj)
            #pragma unroll
            for (int r = 0; r < 16; ++r) {
                int c = w * 64 + ii * 32 + (r & 3) + 8 * (r >> 2) + 4 * lh;
                int p = jj * 32 + lm;
                dst[c * 64 + p] = facc[ii * 2 + jj][r];
            }
}

// ---------------------------------------------------------------------------
// merge_ln: grid 512 = (bq<<1 | poshalf), 256 thr, 32 positions per block.
// (R21 verbatim, proven.)
// ---------------------------------------------------------------------------
__global__ __launch_bounds__(256, 2) void merge_ln_kernel(
    const float* __restrict__ Fp, const float* __restrict__ ln_w,
    const float* __restrict__ ln_b, float* __restrict__ out)
{
    __shared__ float Fs[256 * FM_STRIDE];         // 36864 B
    __shared__ float redS[32 * 32], redQ[32 * 32]; // 8192 B
    __shared__ float lnw_s[256], lnb_s[256];
    __shared__ float mu_s[32], rs_s[32];

    const int t  = threadIdx.x;
    const int bq = blockIdx.x >> 1;
    const int ph = blockIdx.x & 1;
    const int b  = bq >> 6;
    const int p0 = (bq & 63) * 64 + ph * 32;

    lnw_s[t] = ln_w[t]; lnb_s[t] = ln_b[t];

    const int pb = (t & 7) * 4;       // 4 consecutive positions (of 32)
    const int cg = t >> 3;            // 32 groups x 8 channels
    const float* base = Fp + (size_t)bq * 2 * (CDIM * 64) + ph * 32;

    f32x4 s4 = {}, q4 = {};
    #pragma unroll
    for (int ci = 0; ci < 8; ++ci) {
        int c = cg * 8 + ci;
        size_t off = (size_t)c * 64 + pb;
        f32x4 v = *(const f32x4*)(base + off);
        v += *(const f32x4*)(base + (size_t)(CDIM * 64) + off);
        *(f32x4*)&Fs[c * FM_STRIDE + pb] = v;
        s4 += v; q4 += v * v;
    }
    #pragma unroll
    for (int k2 = 0; k2 < 4; ++k2) {
        redS[cg * 32 + pb + k2] = s4[k2];
        redQ[cg * 32 + pb + k2] = q4[k2];
    }
    __syncthreads();
    if (t < 32) {
        float ss = 0.f, qq = 0.f;
        #pragma unroll
        for (int g2 = 0; g2 < 32; ++g2) { ss += redS[g2 * 32 + t]; qq += redQ[g2 * 32 + t]; }
        float mean = ss * (1.0f / 256.0f);
        float var  = qq * (1.0f / 256.0f) - mean * mean;
        mu_s[t] = mean;
        rs_s[t] = rsqrtf(var + EPSV);
    }
    __syncthreads();
    const int p   = t & 31;
    const int cg2 = t >> 5;           // 8 groups x 32 channels
    const float mu = mu_s[p], rs = rs_s[p];
    float* dst = out + (size_t)b * CDIM * NPOS + p0 + p;
    #pragma unroll 4
    for (int ci = 0; ci < 32; ++ci) {
        int c = cg2 * 32 + ci;
        dst[(size_t)c * NPOS] = (Fs[c * FM_STRIDE + p] - mu) * rs * lnw_s[c] + lnb_s[c];
    }
}

// ---------------------------------------------------------------------------
extern "C" void kernel_launch(void* const* d_in, const int* in_sizes, int n_in,
                              void* d_out, int out_size, void* d_ws, size_t ws_size,
                              hipStream_t stream)
{
    const float* x1  = (const float*)d_in[0];
    const float* x2  = (const float*)d_in[1];
    const float* qw  = (const float*)d_in[2];
    const float* qb  = (const float*)d_in[3];
    const float* kw  = (const float*)d_in[4];
    const float* kb  = (const float*)d_in[5];
    const float* vw  = (const float*)d_in[6];
    const float* vb  = (const float*)d_in[7];
    const float* lnw = (const float*)d_in[8];
    const float* lnb = (const float*)d_in[9];

    const size_t tsz = (size_t)BATCH * NPOS * CDIM;
    f16* Qg  = (f16*)d_ws;
    f16* Kg  = Qg + tsz;
    f16* Vf  = Kg + tsz;                          // fragment-major V
    f16* Wf  = Vf + tsz;                          // 384 KB fragment-major W
    float* Fp = (float*)(Wf + 3 * CDIM * CDIM);   // 32 MB fp32; total ws ~57 MB

    wconv_kernel<<<24, 256, 0, stream>>>(qw, kw, vw, Wf);
    gemm_kernel<<<768, 256, 0, stream>>>(x1, x2, Wf, qb, kb, vb, Qg, Kg, Vf);
    attn_kernel<<<512, 256, 0, stream>>>(Qg, Kg, Vf, Fp);
    merge_ln_kernel<<<512, 256, 0, stream>>>(Fp, lnw, lnb, (float*)d_out);
}